// Round 3
// 1073.816 us; speedup vs baseline: 1.3116x; 1.3116x over previous
//
#include <hip/hip_runtime.h>

typedef __attribute__((ext_vector_type(8))) short short8;
typedef __attribute__((ext_vector_type(4))) float float4v;
typedef unsigned short ushort_t;

#define N_SAMPLES 65536
#define IN_DIM 2051
#define NET_K 2048
#define NPAD 128           // HIDDEN=100 padded to 128
#define EPSV 1e-5f

// ---- workspace layout (bytes) ----
// WT   : folded bf16 W_net^T  [128][2048]           524288
// BP   : folded b_net fp32    [128]                  512
// B1F  : folded b1  fp32      [8][50]                1600
// W1F  : folded W1  fp32      [8][100][50]           160000
// W2F  : folded W2  fp32      [8][50][128]           204800
// B2F  : folded b2  fp32      [8][128]               4096
// CNT  : per-head counters    [8] (+pad)             64
// BKT  : buckets int          [8][65536]             2097152
// H    : stage1 out fp32      [65536][128]           33554432
static constexpr size_t OFF_WT  = 0;
static constexpr size_t OFF_BP  = 524288;
static constexpr size_t OFF_B1F = 524800;
static constexpr size_t OFF_W1F = 526400;
static constexpr size_t OFF_W2F = 686400;
static constexpr size_t OFF_B2F = 891200;
static constexpr size_t OFF_CNT = 895296;
static constexpr size_t OFF_BKT = 895360;
static constexpr size_t OFF_H   = 2992512;

__device__ __forceinline__ ushort_t f2bf(float f) {
    union { float f; unsigned u; } c; c.f = f;
    unsigned r = (c.u + 0x7FFFu + ((c.u >> 16) & 1u)) >> 16;  // RNE
    return (ushort_t)r;
}

// ---------- prep: W'T[n][k] = bf16( W_net[k][n] * rsqrt(var0[k]+eps) ), zero-pad n>=100
__global__ void fold_wnet(const float* __restrict__ W_net, const float* __restrict__ var0,
                          ushort_t* __restrict__ WT) {
    int id = blockIdx.x * 256 + threadIdx.x;     // 262144 = 128*2048
    int k = id & 2047, n = id >> 11;
    float v = 0.f;
    if (n < 100) v = W_net[k * 100 + n] * rsqrtf(var0[k] + EPSV);
    WT[(size_t)n * 2048 + k] = f2bf(v);
}

// ---------- prep: b'[j] = b_net[j] - sum_k mean0[k]*s0[k]*W_net[k][j]; zero-pad
__global__ void fold_bnet(const float* __restrict__ W_net, const float* __restrict__ mean0,
                          const float* __restrict__ var0, const float* __restrict__ b_net,
                          float* __restrict__ bp) {
    int j = blockIdx.x, t = threadIdx.x;
    __shared__ float red[256];
    float s = 0.f;
    if (j < 100)
        for (int k = t; k < NET_K; k += 256)
            s += mean0[k] * rsqrtf(var0[k] + EPSV) * W_net[k * 100 + j];
    red[t] = s; __syncthreads();
    for (int w = 128; w > 0; w >>= 1) { if (t < w) red[t] += red[t + w]; __syncthreads(); }
    if (t == 0) bp[j] = (j < 100) ? (b_net[j] - red[0]) : 0.f;
}

// ---------- prep: fold bn1 into W1/b1, bn2 into W2/b2 (one block per head)
__global__ void fold_heads(const float* __restrict__ m1, const float* __restrict__ v1,
                           const float* __restrict__ W1, const float* __restrict__ b1,
                           const float* __restrict__ m2, const float* __restrict__ v2,
                           const float* __restrict__ W2, const float* __restrict__ b2,
                           float* __restrict__ W1f, float* __restrict__ b1f,
                           float* __restrict__ W2f, float* __restrict__ b2f) {
    int hd = blockIdx.x, t = threadIdx.x;
    const float* W1h = W1 + hd * 5000; float* W1fh = W1f + hd * 5000;
    for (int id = t; id < 5000; id += 256) {
        int k = id / 50;
        W1fh[id] = rsqrtf(v1[k] + EPSV) * W1h[id];
    }
    if (t < 50) {
        float s = 0.f;
        for (int k = 0; k < 100; k++) s += m1[k] * rsqrtf(v1[k] + EPSV) * W1h[k * 50 + t];
        b1f[hd * 50 + t] = b1[hd * 50 + t] - s;
    }
    const float* W2h = W2 + hd * 6400; float* W2fh = W2f + hd * 6400;
    const float* m2h = m2 + hd * 50;   const float* v2h = v2 + hd * 50;
    for (int id = t; id < 6400; id += 256) {
        int o = id >> 7;
        W2fh[id] = rsqrtf(v2h[o] + EPSV) * W2h[id];
    }
    if (t < 128) {
        float s = 0.f;
        for (int o = 0; o < 50; o++) s += m2h[o] * rsqrtf(v2h[o] + EPSV) * W2h[o * 128 + t];
        b2f[hd * 128 + t] = b2[hd * 128 + t] - s;
    }
}

// ---------- bin samples by head: block-local LDS histogram, 8 global atomics/block
// Side effect: bucket entries are contiguous ascending-sid runs of 256 -> better
// gather locality in heads_mlp.
__global__ __launch_bounds__(256) void bin_heads(const float* __restrict__ x,
                                                 int* __restrict__ cnt,
                                                 int* __restrict__ bkt) {
    __shared__ int lcnt[8];
    __shared__ int lbase[8];
    int t = threadIdx.x;
    if (t < 8) lcnt[t] = 0;
    __syncthreads();
    int sid = blockIdx.x * 256 + t;
    const float* xr = x + (size_t)sid * IN_DIM;
    float x0 = xr[0], x1 = xr[1], x2 = xr[2];
    bool b0 = x0 > 0.5f, b1 = x1 > 0.5f, b2 = x2 > 0.5f;
    bool l0 = (1.0f - x0) > 0.5f, l1 = (1.0f - x1) > 0.5f, l2 = (1.0f - x2) > 0.5f;
    int idx;
    if ((l0 || b0) && (l1 || b1) && (l2 || b2))
        idx = (b0 ? 4 : 0) | (b1 ? 2 : 0) | (b2 ? 1 : 0);
    else
        idx = 0;  // argmax of all-False == 0
    int pos = atomicAdd(&lcnt[idx], 1);    // LDS atomic, block-local
    __syncthreads();
    if (t < 8) lbase[t] = atomicAdd(&cnt[t], lcnt[t]);   // 8 global atomics/block
    __syncthreads();
    bkt[idx * N_SAMPLES + lbase[idx] + pos] = sid;
}

// ---------- stage 1: h = relu(x[:,3:2051] @ W' + b')   (bf16 MFMA, fp32 acc)
// Barrier-free: WT (512 KB) is L2-resident; read B-fragments directly from
// global (16B/lane, 16B-aligned) instead of staging through LDS.
// M-tile 64 (4 waves x 16 rows), N=128 (8 n-tiles), K streamed in 64 steps of 32.
__global__ __launch_bounds__(256, 4) void gemm1(const float* __restrict__ x,
                                                const ushort_t* __restrict__ WT,
                                                const float* __restrict__ bp,
                                                float* __restrict__ h) {
    const int tid = threadIdx.x;
    const int wave = tid >> 6, lane = tid & 63;
    const int lrow = lane & 15;     // m of A-frag / n of B-frag / col of C
    const int lquad = lane >> 4;    // 0..3
    const int mBase = blockIdx.x * 64 + wave * 16;
    const float* xrow = x + (size_t)(mBase + lrow) * IN_DIM + 3;

    float4v acc[8];
    const float4v zero4 = {0.f, 0.f, 0.f, 0.f};
#pragma unroll
    for (int i = 0; i < 8; i++) acc[i] = zero4;

    for (int ks = 0; ks < 64; ++ks) {
        const int k0 = ks * 32 + lquad * 8;
        const float* ap = xrow + k0;
        short8 afrag;
#pragma unroll
        for (int j = 0; j < 8; ++j) afrag[j] = (short)f2bf(ap[j]);
#pragma unroll
        for (int nt = 0; nt < 8; ++nt) {
            short8 bfrag = *(const short8*)(WT + (size_t)(nt * 16 + lrow) * 2048 + k0);
            acc[nt] = __builtin_amdgcn_mfma_f32_16x16x32_bf16(afrag, bfrag, acc[nt], 0, 0, 0);
        }
    }
    // epilogue: D row=(lane>>4)*4+reg, col=lane&15
#pragma unroll
    for (int nt = 0; nt < 8; ++nt) {
        int n = nt * 16 + lrow;
        float bv = bp[n];
#pragma unroll
        for (int r = 0; r < 4; ++r) {
            int m = mBase + lquad * 4 + r;
            float v = acc[nt][r] + bv;
            h[(size_t)m * NPAD + n] = v > 0.f ? v : 0.f;
        }
    }
}

// ---------- stage 2: per-head MLP, one thread per sample, weights wave-uniform
__global__ __launch_bounds__(256) void heads_mlp(const float* __restrict__ h,
                                                 const int* __restrict__ cnt,
                                                 const int* __restrict__ bkt,
                                                 const float* __restrict__ W1f,
                                                 const float* __restrict__ b1f,
                                                 const float* __restrict__ W2f,
                                                 const float* __restrict__ b2f,
                                                 float* __restrict__ out) {
    int hd = blockIdx.x >> 8;                       // 256 blocks per head
    int slot = (blockIdx.x & 255) * 256 + threadIdx.x;
    if (slot >= cnt[hd]) return;
    int sid = bkt[hd * N_SAMPLES + slot];
    const float* hv = h + (size_t)sid * NPAD;
    const float* W1h = W1f + hd * 5000;
    const float* b1h = b1f + hd * 50;

    float t1[50];
#pragma unroll
    for (int j = 0; j < 50; j++) t1[j] = b1h[j];
    const float4v* hv4 = (const float4v*)hv;
    for (int k4 = 0; k4 < 25; k4++) {               // vectorized gather: 25 x float4
        float4v hk = hv4[k4];
#pragma unroll
        for (int jj = 0; jj < 4; jj++) {
            float hkj = hk[jj];
#pragma unroll
            for (int j = 0; j < 50; j++) t1[j] += hkj * W1h[(k4 * 4 + jj) * 50 + j];
        }
    }
#pragma unroll
    for (int j = 0; j < 50; j++) t1[j] = t1[j] > 0.f ? t1[j] : 0.f;

    const float* W2h = W2f + hd * 6400;
    const float* b2h = b2f + hd * 128;
    float* op = out + (size_t)sid * 128;
#pragma unroll 1
    for (int c = 0; c < 4; c++) {
        float acc[32];
#pragma unroll
        for (int o = 0; o < 32; o++) acc[o] = b2h[c * 32 + o];
        for (int j = 0; j < 50; j++) {
            float tj = t1[j];
#pragma unroll
            for (int o = 0; o < 32; o++) acc[o] += tj * W2h[j * 128 + c * 32 + o];
        }
        float4v* op4 = (float4v*)(op + c * 32);
#pragma unroll
        for (int q = 0; q < 8; q++) {               // vectorized store: 8 x float4
            float4v v = {acc[4 * q], acc[4 * q + 1], acc[4 * q + 2], acc[4 * q + 3]};
            op4[q] = v;
        }
    }
}

extern "C" void kernel_launch(void* const* d_in, const int* in_sizes, int n_in,
                              void* d_out, int out_size, void* d_ws, size_t ws_size,
                              hipStream_t stream) {
    const float* x        = (const float*)d_in[0];
    const float* bn0_mean = (const float*)d_in[1];
    const float* bn0_var  = (const float*)d_in[2];
    const float* W_net    = (const float*)d_in[3];
    const float* b_net    = (const float*)d_in[4];
    const float* bn1_mean = (const float*)d_in[5];
    const float* bn1_var  = (const float*)d_in[6];
    const float* W1       = (const float*)d_in[7];
    const float* b1       = (const float*)d_in[8];
    const float* bn2_mean = (const float*)d_in[9];
    const float* bn2_var  = (const float*)d_in[10];
    const float* W2       = (const float*)d_in[11];
    const float* b2       = (const float*)d_in[12];
    float* out = (float*)d_out;
    char* ws = (char*)d_ws;

    ushort_t* WT  = (ushort_t*)(ws + OFF_WT);
    float* BP     = (float*)(ws + OFF_BP);
    float* B1F    = (float*)(ws + OFF_B1F);
    float* W1F    = (float*)(ws + OFF_W1F);
    float* W2F    = (float*)(ws + OFF_W2F);
    float* B2F    = (float*)(ws + OFF_B2F);
    int*   CNT    = (int*)(ws + OFF_CNT);
    int*   BKT    = (int*)(ws + OFF_BKT);
    float* H      = (float*)(ws + OFF_H);

    hipMemsetAsync(ws + OFF_CNT, 0, 64, stream);
    fold_wnet<<<1024, 256, 0, stream>>>(W_net, bn0_var, WT);
    fold_bnet<<<128, 256, 0, stream>>>(W_net, bn0_mean, bn0_var, b_net, BP);
    fold_heads<<<8, 256, 0, stream>>>(bn1_mean, bn1_var, W1, b1,
                                      bn2_mean, bn2_var, W2, b2,
                                      W1F, B1F, W2F, B2F);
    bin_heads<<<N_SAMPLES / 256, 256, 0, stream>>>(x, CNT, BKT);
    gemm1<<<N_SAMPLES / 64, 256, 0, stream>>>(x, WT, BP, H);
    heads_mlp<<<8 * 256, 256, 0, stream>>>(H, CNT, BKT, W1F, B1F, W2F, B2F, out);
}

// Round 4
// 1035.951 us; speedup vs baseline: 1.3596x; 1.0366x over previous
//
#include <hip/hip_runtime.h>

typedef __attribute__((ext_vector_type(8))) short short8;
typedef __attribute__((ext_vector_type(4))) float float4v;
typedef unsigned short ushort_t;

#define N_SAMPLES 65536
#define IN_DIM 2051
#define NET_K 2048
#define NPAD 128           // HIDDEN=100 padded to 128
#define EPSV 1e-5f

// ---- workspace layout (bytes) ----
static constexpr size_t OFF_WT  = 0;
static constexpr size_t OFF_BP  = 524288;
static constexpr size_t OFF_B1F = 524800;
static constexpr size_t OFF_W1F = 526400;
static constexpr size_t OFF_W2F = 686400;
static constexpr size_t OFF_B2F = 891200;
static constexpr size_t OFF_CNT = 895296;
static constexpr size_t OFF_BKT = 895360;
static constexpr size_t OFF_H   = 2992512;

__device__ __forceinline__ ushort_t f2bf(float f) {
    union { float f; unsigned u; } c; c.f = f;
    unsigned r = (c.u + 0x7FFFu + ((c.u >> 16) & 1u)) >> 16;  // RNE
    return (ushort_t)r;
}

// ---------- prep: W'T[n][k] = bf16( W_net[k][n] * rsqrt(var0[k]+eps) ), zero-pad n>=100
__global__ void fold_wnet(const float* __restrict__ W_net, const float* __restrict__ var0,
                          ushort_t* __restrict__ WT) {
    int id = blockIdx.x * 256 + threadIdx.x;     // 262144 = 128*2048
    int k = id & 2047, n = id >> 11;
    float v = 0.f;
    if (n < 100) v = W_net[k * 100 + n] * rsqrtf(var0[k] + EPSV);
    WT[(size_t)n * 2048 + k] = f2bf(v);
}

// ---------- prep: b'[j] = b_net[j] - sum_k mean0[k]*s0[k]*W_net[k][j]; zero-pad
__global__ void fold_bnet(const float* __restrict__ W_net, const float* __restrict__ mean0,
                          const float* __restrict__ var0, const float* __restrict__ b_net,
                          float* __restrict__ bp) {
    int j = blockIdx.x, t = threadIdx.x;
    __shared__ float red[256];
    float s = 0.f;
    if (j < 100)
        for (int k = t; k < NET_K; k += 256)
            s += mean0[k] * rsqrtf(var0[k] + EPSV) * W_net[k * 100 + j];
    red[t] = s; __syncthreads();
    for (int w = 128; w > 0; w >>= 1) { if (t < w) red[t] += red[t + w]; __syncthreads(); }
    if (t == 0) bp[j] = (j < 100) ? (b_net[j] - red[0]) : 0.f;
}

// ---------- prep: fold bn1 into W1/b1, bn2 into W2/b2 (one block per head)
__global__ void fold_heads(const float* __restrict__ m1, const float* __restrict__ v1,
                           const float* __restrict__ W1, const float* __restrict__ b1,
                           const float* __restrict__ m2, const float* __restrict__ v2,
                           const float* __restrict__ W2, const float* __restrict__ b2,
                           float* __restrict__ W1f, float* __restrict__ b1f,
                           float* __restrict__ W2f, float* __restrict__ b2f) {
    int hd = blockIdx.x, t = threadIdx.x;
    const float* W1h = W1 + hd * 5000; float* W1fh = W1f + hd * 5000;
    for (int id = t; id < 5000; id += 256) {
        int k = id / 50;
        W1fh[id] = rsqrtf(v1[k] + EPSV) * W1h[id];
    }
    if (t < 50) {
        float s = 0.f;
        for (int k = 0; k < 100; k++) s += m1[k] * rsqrtf(v1[k] + EPSV) * W1h[k * 50 + t];
        b1f[hd * 50 + t] = b1[hd * 50 + t] - s;
    }
    const float* W2h = W2 + hd * 6400; float* W2fh = W2f + hd * 6400;
    const float* m2h = m2 + hd * 50;   const float* v2h = v2 + hd * 50;
    for (int id = t; id < 6400; id += 256) {
        int o = id >> 7;
        W2fh[id] = rsqrtf(v2h[o] + EPSV) * W2h[id];
    }
    if (t < 128) {
        float s = 0.f;
        for (int o = 0; o < 50; o++) s += m2h[o] * rsqrtf(v2h[o] + EPSV) * W2h[o * 128 + t];
        b2f[hd * 128 + t] = b2[hd * 128 + t] - s;
    }
}

// ---------- bin samples by head: block-local LDS histogram, 8 global atomics/block
__global__ __launch_bounds__(256) void bin_heads(const float* __restrict__ x,
                                                 int* __restrict__ cnt,
                                                 int* __restrict__ bkt) {
    __shared__ int lcnt[8];
    __shared__ int lbase[8];
    int t = threadIdx.x;
    if (t < 8) lcnt[t] = 0;
    __syncthreads();
    int sid = blockIdx.x * 256 + t;
    const float* xr = x + (size_t)sid * IN_DIM;
    float x0 = xr[0], x1 = xr[1], x2 = xr[2];
    bool b0 = x0 > 0.5f, b1 = x1 > 0.5f, b2 = x2 > 0.5f;
    bool l0 = (1.0f - x0) > 0.5f, l1 = (1.0f - x1) > 0.5f, l2 = (1.0f - x2) > 0.5f;
    int idx;
    if ((l0 || b0) && (l1 || b1) && (l2 || b2))
        idx = (b0 ? 4 : 0) | (b1 ? 2 : 0) | (b2 ? 1 : 0);
    else
        idx = 0;  // argmax of all-False == 0
    int pos = atomicAdd(&lcnt[idx], 1);    // LDS atomic, block-local
    __syncthreads();
    if (t < 8) lbase[t] = atomicAdd(&cnt[t], lcnt[t]);   // 8 global atomics/block
    __syncthreads();
    bkt[idx * N_SAMPLES + lbase[idx] + pos] = sid;
}

// ---------- stage 1: h = relu(x[:,3:2051] @ W' + b')   (bf16 MFMA, fp32 acc)
// Latency-bound fix (R3): explicit register double-buffering of A and B operands,
// ks-loop unrolled x2 (ping-pong, no copies). 7 n-tiles (112 >= HIDDEN=100) —
// nt=7 was pure zero-padding. ~115 VGPR, fits __launch_bounds__(256,4).
__global__ __launch_bounds__(256, 4) void gemm1(const float* __restrict__ x,
                                                const ushort_t* __restrict__ WT,
                                                const float* __restrict__ bp,
                                                float* __restrict__ h) {
    const int tid = threadIdx.x;
    const int wave = tid >> 6, lane = tid & 63;
    const int lrow = lane & 15;     // m of A-frag / n of B-frag / col of C
    const int lquad = lane >> 4;    // 0..3
    const int mBase = blockIdx.x * 64 + wave * 16;
    const float* xrow = x + (size_t)(mBase + lrow) * IN_DIM + 3 + lquad * 8;
    const ushort_t* wrow = WT + (size_t)lrow * 2048 + lquad * 8;

    float4v acc[7];
#pragma unroll
    for (int i = 0; i < 7; i++) acc[i] = (float4v){0.f, 0.f, 0.f, 0.f};

    float a0[8], a1[8];
    short8 bb0[7], bb1[7];

    // prime ks=0 into buffer 0
#pragma unroll
    for (int j = 0; j < 8; ++j) a0[j] = xrow[j];
#pragma unroll
    for (int nt = 0; nt < 7; ++nt)
        bb0[nt] = *(const short8*)(wrow + (size_t)nt * (16 * 2048));

    for (int ks = 0; ks < 64; ks += 2) {
        // prefetch ks+1 into buffer 1 (ks max 62 -> ks+1 <= 63, in bounds)
        {
            const float* ap = xrow + (ks + 1) * 32;
            const ushort_t* bpp = wrow + (ks + 1) * 32;
#pragma unroll
            for (int j = 0; j < 8; ++j) a1[j] = ap[j];
#pragma unroll
            for (int nt = 0; nt < 7; ++nt)
                bb1[nt] = *(const short8*)(bpp + (size_t)nt * (16 * 2048));
        }
        // compute ks with buffer 0
        {
            short8 af;
#pragma unroll
            for (int j = 0; j < 8; ++j) af[j] = (short)f2bf(a0[j]);
#pragma unroll
            for (int nt = 0; nt < 7; ++nt)
                acc[nt] = __builtin_amdgcn_mfma_f32_16x16x32_bf16(af, bb0[nt], acc[nt], 0, 0, 0);
        }
        // prefetch ks+2 into buffer 0 (clamped; last-iteration loads are discarded)
        {
            const int kp = (ks + 2 < 64) ? ks + 2 : 63;
            const float* ap = xrow + kp * 32;
            const ushort_t* bpp = wrow + kp * 32;
#pragma unroll
            for (int j = 0; j < 8; ++j) a0[j] = ap[j];
#pragma unroll
            for (int nt = 0; nt < 7; ++nt)
                bb0[nt] = *(const short8*)(bpp + (size_t)nt * (16 * 2048));
        }
        // compute ks+1 with buffer 1
        {
            short8 af;
#pragma unroll
            for (int j = 0; j < 8; ++j) af[j] = (short)f2bf(a1[j]);
#pragma unroll
            for (int nt = 0; nt < 7; ++nt)
                acc[nt] = __builtin_amdgcn_mfma_f32_16x16x32_bf16(af, bb1[nt], acc[nt], 0, 0, 0);
        }
    }

    // epilogue: D row=(lane>>4)*4+reg, col=lane&15
#pragma unroll
    for (int nt = 0; nt < 7; ++nt) {
        int n = nt * 16 + lrow;
        float bv = bp[n];
#pragma unroll
        for (int r = 0; r < 4; ++r) {
            int m = mBase + lquad * 4 + r;
            float v = acc[nt][r] + bv;
            h[(size_t)m * NPAD + n] = v > 0.f ? v : 0.f;
        }
    }
}

// ---------- stage 2: per-head MLP, one thread per sample, weights wave-uniform
__global__ __launch_bounds__(256) void heads_mlp(const float* __restrict__ h,
                                                 const int* __restrict__ cnt,
                                                 const int* __restrict__ bkt,
                                                 const float* __restrict__ W1f,
                                                 const float* __restrict__ b1f,
                                                 const float* __restrict__ W2f,
                                                 const float* __restrict__ b2f,
                                                 float* __restrict__ out) {
    int hd = blockIdx.x >> 8;                       // 256 blocks per head
    int slot = (blockIdx.x & 255) * 256 + threadIdx.x;
    if (slot >= cnt[hd]) return;
    int sid = bkt[hd * N_SAMPLES + slot];
    const float* hv = h + (size_t)sid * NPAD;
    const float* W1h = W1f + hd * 5000;
    const float* b1h = b1f + hd * 50;

    float t1[50];
#pragma unroll
    for (int j = 0; j < 50; j++) t1[j] = b1h[j];
    const float4v* hv4 = (const float4v*)hv;
    for (int k4 = 0; k4 < 25; k4++) {               // vectorized gather: 25 x float4
        float4v hk = hv4[k4];
#pragma unroll
        for (int jj = 0; jj < 4; jj++) {
            float hkj = hk[jj];
#pragma unroll
            for (int j = 0; j < 50; j++) t1[j] += hkj * W1h[(k4 * 4 + jj) * 50 + j];
        }
    }
#pragma unroll
    for (int j = 0; j < 50; j++) t1[j] = t1[j] > 0.f ? t1[j] : 0.f;

    const float* W2h = W2f + hd * 6400;
    const float* b2h = b2f + hd * 128;
    float* op = out + (size_t)sid * 128;
#pragma unroll 1
    for (int c = 0; c < 4; c++) {
        float acc[32];
#pragma unroll
        for (int o = 0; o < 32; o++) acc[o] = b2h[c * 32 + o];
        for (int j = 0; j < 50; j++) {
            float tj = t1[j];
#pragma unroll
            for (int o = 0; o < 32; o++) acc[o] += tj * W2h[j * 128 + c * 32 + o];
        }
        float4v* op4 = (float4v*)(op + c * 32);
#pragma unroll
        for (int q = 0; q < 8; q++) {               // vectorized store: 8 x float4
            float4v v = {acc[4 * q], acc[4 * q + 1], acc[4 * q + 2], acc[4 * q + 3]};
            op4[q] = v;
        }
    }
}

extern "C" void kernel_launch(void* const* d_in, const int* in_sizes, int n_in,
                              void* d_out, int out_size, void* d_ws, size_t ws_size,
                              hipStream_t stream) {
    const float* x        = (const float*)d_in[0];
    const float* bn0_mean = (const float*)d_in[1];
    const float* bn0_var  = (const float*)d_in[2];
    const float* W_net    = (const float*)d_in[3];
    const float* b_net    = (const float*)d_in[4];
    const float* bn1_mean = (const float*)d_in[5];
    const float* bn1_var  = (const float*)d_in[6];
    const float* W1       = (const float*)d_in[7];
    const float* b1       = (const float*)d_in[8];
    const float* bn2_mean = (const float*)d_in[9];
    const float* bn2_var  = (const float*)d_in[10];
    const float* W2       = (const float*)d_in[11];
    const float* b2       = (const float*)d_in[12];
    float* out = (float*)d_out;
    char* ws = (char*)d_ws;

    ushort_t* WT  = (ushort_t*)(ws + OFF_WT);
    float* BP     = (float*)(ws + OFF_BP);
    float* B1F    = (float*)(ws + OFF_B1F);
    float* W1F    = (float*)(ws + OFF_W1F);
    float* W2F    = (float*)(ws + OFF_W2F);
    float* B2F    = (float*)(ws + OFF_B2F);
    int*   CNT    = (int*)(ws + OFF_CNT);
    int*   BKT    = (int*)(ws + OFF_BKT);
    float* H      = (float*)(ws + OFF_H);

    hipMemsetAsync(ws + OFF_CNT, 0, 64, stream);
    fold_wnet<<<1024, 256, 0, stream>>>(W_net, bn0_var, WT);
    fold_bnet<<<128, 256, 0, stream>>>(W_net, bn0_mean, bn0_var, b_net, BP);
    fold_heads<<<8, 256, 0, stream>>>(bn1_mean, bn1_var, W1, b1,
                                      bn2_mean, bn2_var, W2, b2,
                                      W1F, B1F, W2F, B2F);
    bin_heads<<<N_SAMPLES / 256, 256, 0, stream>>>(x, CNT, BKT);
    gemm1<<<N_SAMPLES / 64, 256, 0, stream>>>(x, WT, BP, H);
    heads_mlp<<<8 * 256, 256, 0, stream>>>(H, CNT, BKT, W1F, B1F, W2F, B2F, out);
}